// Round 7
// baseline (943.684 us; speedup 1.0000x reference)
//
#include <hip/hip_runtime.h>
#include <cstdint>
#include <cmath>

#define T_TOK 8192
#define H_DIM 1024
#define F_DIM 4096
#define NE 8
#define CAP 8192        // perm capacity per expert
#define BK 64
#define BM 256          // token rows per block
#define BN 256          // output cols per block
#define MBLK 16         // max M-blocks (256-row) per expert (4096-token cap)

typedef __attribute__((ext_vector_type(8))) short short8v;
typedef __attribute__((ext_vector_type(4))) float f32x4;

static __device__ __forceinline__ unsigned short f2bf(float f) {
    union { float f; unsigned int u; } v; v.f = f;
    unsigned int r = v.u + 0x7FFFu + ((v.u >> 16) & 1u);  // RNE
    return (unsigned short)(r >> 16);
}

// async global->LDS, 16B per lane; LDS dest is wave-uniform base + lane*16,
// global src is per-lane (supports gather + pre-swizzled source).
static __device__ __forceinline__ void gl_lds16(const void* g, void* l) {
    __builtin_amdgcn_global_load_lds(
        (const __attribute__((address_space(1))) unsigned int*)g,
        (__attribute__((address_space(3))) unsigned int*)l, 16, 0, 0);
}

#define LGKM0  do { asm volatile("s_waitcnt lgkmcnt(0)" ::: "memory"); \
                    __builtin_amdgcn_sched_barrier(0); } while (0)
#define VMCNT0 do { asm volatile("s_waitcnt vmcnt(0)" ::: "memory"); \
                    __builtin_amdgcn_sched_barrier(0); } while (0)
#define BAR    do { __builtin_amdgcn_s_barrier(); \
                    __builtin_amdgcn_sched_barrier(0); } while (0)

// ---------------- router: logits, top-2, weights, compaction, inverse map, x->bf16 ----------------
__global__ void router_k(const float* __restrict__ x, const float* __restrict__ Wr,
                         const float* __restrict__ br,
                         int* __restrict__ cnt, int* __restrict__ perm,
                         int* __restrict__ inv, float* __restrict__ tw,
                         unsigned short* __restrict__ xb)
{
    const int wave = threadIdx.x >> 6;
    const int lane = threadIdx.x & 63;
    const int t = blockIdx.x * 4 + wave;
    const float* xr = x + (size_t)t * H_DIM;
    float acc[NE];
#pragma unroll
    for (int e = 0; e < NE; ++e) acc[e] = 0.f;
#pragma unroll
    for (int c0 = 0; c0 < H_DIM; c0 += 256) {
        const float4 v = *(const float4*)(xr + c0 + lane * 4);
        ushort4 ob;
        ob.x = f2bf(v.x); ob.y = f2bf(v.y); ob.z = f2bf(v.z); ob.w = f2bf(v.w);
        *(ushort4*)(xb + (size_t)t * H_DIM + c0 + lane * 4) = ob;
        const int hbase = c0 + lane * 4;
        float vv[4] = {v.x, v.y, v.z, v.w};
#pragma unroll
        for (int i = 0; i < 4; ++i) {
            const float4 w0 = *(const float4*)(Wr + (size_t)(hbase + i) * NE);
            const float4 w1 = *(const float4*)(Wr + (size_t)(hbase + i) * NE + 4);
            acc[0] += vv[i] * w0.x; acc[1] += vv[i] * w0.y;
            acc[2] += vv[i] * w0.z; acc[3] += vv[i] * w0.w;
            acc[4] += vv[i] * w1.x; acc[5] += vv[i] * w1.y;
            acc[6] += vv[i] * w1.z; acc[7] += vv[i] * w1.w;
        }
    }
#pragma unroll
    for (int off = 32; off > 0; off >>= 1) {
#pragma unroll
        for (int e = 0; e < NE; ++e) acc[e] += __shfl_xor(acc[e], off, 64);
    }
    if (lane == 0) {
#pragma unroll
        for (int e = 0; e < NE; ++e) acc[e] += br[e];
        int i0 = 0; float l0 = acc[0];
#pragma unroll
        for (int e = 1; e < NE; ++e) if (acc[e] > l0) { l0 = acc[e]; i0 = e; }
        int i1 = -1; float l1 = -3.4e38f;
#pragma unroll
        for (int e = 0; e < NE; ++e) if (e != i0 && acc[e] > l1) { l1 = acc[e]; i1 = e; }
        // top-2 renormalized softmax weights from logits (exact)
        const float w0 = 1.f / (1.f + expf(l1 - l0));
        const int p0 = atomicAdd(&cnt[i0], 1);
        perm[i0 * CAP + p0] = t;
        const int p1 = atomicAdd(&cnt[i1], 1);
        perm[i1 * CAP + p1] = t;
        inv[2 * t + 0] = (i0 << 13) | p0;  tw[2 * t + 0] = w0;
        inv[2 * t + 1] = (i1 << 13) | p1;  tw[2 * t + 1] = 1.f - w0;
    }
}

// ---------------- 256-aligned exclusive prefix of counts ----------------
__global__ void prefix_k(const int* __restrict__ cnt, int* __restrict__ offs)
{
    if (threadIdx.x == 0 && blockIdx.x == 0) {
        int o = 0;
        for (int e = 0; e < NE; ++e) { offs[e] = o; o += ((cnt[e] + 255) >> 8) << 8; }
        offs[NE] = o;
    }
}

// ---------------- transpose + fp32->bf16 convert: in[E][R][C] -> out[E][C][R] ----------------
__global__ __launch_bounds__(256) void tcvt_k(const float* __restrict__ in,
                                              unsigned short* __restrict__ out,
                                              int R, int C)
{
    __shared__ float tile[64][65];
    const int e = blockIdx.z;
    const int r0 = blockIdx.y * 64, c0 = blockIdx.x * 64;
    const float* ip = in + (size_t)e * R * C;
    unsigned short* op = out + (size_t)e * R * C;
    const int j = threadIdx.x;
    const int lr = j >> 4, lc = (j & 15) * 4;
#pragma unroll
    for (int p = 0; p < 4; ++p) {
        const float4 v = *(const float4*)(ip + (size_t)(r0 + lr + p * 16) * C + c0 + lc);
        tile[lr + p * 16][lc + 0] = v.x;
        tile[lr + p * 16][lc + 1] = v.y;
        tile[lr + p * 16][lc + 2] = v.z;
        tile[lr + p * 16][lc + 3] = v.w;
    }
    __syncthreads();
#pragma unroll
    for (int p = 0; p < 4; ++p) {
        const int orow = lr + p * 16;
        ushort4 o;
        o.x = f2bf(tile[lc + 0][orow]);
        o.y = f2bf(tile[lc + 1][orow]);
        o.z = f2bf(tile[lc + 2][orow]);
        o.w = f2bf(tile[lc + 3][orow]);
        *(ushort4*)(op + (size_t)(c0 + orow) * R + r0 + lc) = o;
    }
}

// ---- per-phase body: stage 1 half-tile of tile tau+1, ds_read a-frags for
// quadrant q (b-frags once per tile at q==0), lgkm0, setprio'd 16 MFMA. ----
// Uses locals: tnext, NT_, k1, nxt, cur, pA, pB, dA, dB, smem, b, a, acc,
// wm, wn, fr, fg (identical names in both GEMM kernels).
#define PH(q) do {                                                              \
    if (tnext < NT_) {                                                          \
        if ((q) == 0) { gl_lds16(pA[0] + k1, smem + nxt + dA[0]);               \
                        gl_lds16(pA[1] + k1, smem + nxt + dA[1]); }             \
        if ((q) == 1) { gl_lds16(pA[2] + k1, smem + nxt + dA[2]);               \
                        gl_lds16(pA[3] + k1, smem + nxt + dA[3]); }             \
        if ((q) == 2) { gl_lds16(pB[0] + k1, smem + nxt + dB[0]);               \
                        gl_lds16(pB[1] + k1, smem + nxt + dB[1]); }             \
        if ((q) == 3) { gl_lds16(pB[2] + k1, smem + nxt + dB[2]);               \
                        gl_lds16(pB[3] + k1, smem + nxt + dB[3]); }             \
    }                                                                           \
    if ((q) == 0) {                                                             \
        _Pragma("unroll") for (int kk = 0; kk < 2; ++kk)                        \
        _Pragma("unroll") for (int n = 0; n < 4; ++n) {                         \
            const int R = wn * 64 + n * 16 + fr;                                \
            b[kk][n] = *(const short8v*)(smem + cur + 16384 + R * 64 +          \
                                         (((kk * 4 + fg) ^ (R & 7)) * 8));      \
        }                                                                       \
    }                                                                           \
    _Pragma("unroll") for (int kk = 0; kk < 2; ++kk)                            \
    _Pragma("unroll") for (int m2 = 0; m2 < 2; ++m2) {                          \
        const int R = wm * 128 + ((q) * 2 + m2) * 16 + fr;                      \
        a[kk][m2] = *(const short8v*)(smem + cur + R * 64 +                     \
                                      (((kk * 4 + fg) ^ (R & 7)) * 8));         \
    }                                                                           \
    LGKM0;                                                                      \
    __builtin_amdgcn_s_setprio(1);                                              \
    _Pragma("unroll") for (int m2 = 0; m2 < 2; ++m2)                            \
    _Pragma("unroll") for (int n = 0; n < 4; ++n)                               \
    _Pragma("unroll") for (int kk = 0; kk < 2; ++kk)                            \
        acc[(q) * 2 + m2][n] = __builtin_amdgcn_mfma_f32_16x16x32_bf16(         \
            b[kk][n], a[kk][m2], acc[(q) * 2 + m2][n], 0, 0, 0);                \
    __builtin_amdgcn_s_setprio(0);                                              \
} while (0)

#define KLOOP_PIPE(NTV) do {                                                    \
    const int NT_ = (NTV);                                                      \
    _Pragma("unroll") for (int i = 0; i < 4; ++i) gl_lds16(pA[i], smem + dA[i]);\
    _Pragma("unroll") for (int i = 0; i < 4; ++i) gl_lds16(pB[i], smem + dB[i]);\
    VMCNT0; BAR;                                                                \
    for (int tau = 0; tau < NT_; ++tau) {                                       \
        const int cur = (tau & 1) << 15;                                        \
        const int nxt = cur ^ 32768;                                            \
        const int tnext = tau + 1;                                              \
        const int k1 = tnext * BK;                                              \
        PH(0); BAR;                                                             \
        PH(1); BAR;                                                             \
        PH(2); BAR;                                                             \
        PH(3);                                                                  \
        if (tnext < NT_) { VMCNT0; BAR; }                                       \
    }                                                                           \
} while (0)

// ================= GEMM1: h = gelu(gather(x) @ W1[e] + b1[e]) =================
// 256x256 tile, 512 thr (8 waves = 2M x 4N), BK=64, 128KB LDS double-buffer.
// Per K-tile: 4 interleaved phases {stage 1 half-tile of next tile | ds_read
// quadrant | 16 MFMA}; boundary vmcnt(0)+barrier lands on loads with 1-4
// phases of cover. XOR-swizzled src+read, swapped-operand MFMA epilogue.
__global__ __launch_bounds__(512, 2) void gemm1_k(
    const unsigned short* __restrict__ xb,   // [T][H] bf16
    const unsigned short* __restrict__ w1t,  // [E][F][H] bf16 (pre-transposed)
    const float* __restrict__ b1,            // [E][F]
    unsigned short* __restrict__ hbuf,       // [rows][F] bf16
    const int* __restrict__ perm, const int* __restrict__ cnt, const int* __restrict__ offs)
{
    __shared__ __align__(16) unsigned short smem[65536];   // 2 bufs x (A 32KB | B 32KB)
    __shared__ int rows_s[BM];

    constexpr int NY = F_DIM / BN;             // 16
    constexpr int nwg = MBLK * NY * NE;        // 2048
    const int bid = blockIdx.x;
    const int wg = (bid & 7) * (nwg >> 3) + (bid >> 3);   // XCD-aware bijective swizzle
    const int e  = wg / (MBLK * NY);
    const int rem = wg % (MBLK * NY);
    const int nb = rem / MBLK;
    const int mb = rem % MBLK;                 // fastest: same-XCD neighbors share B panel

    const int c = cnt[e];
    const int m0 = mb * BM;
    if (m0 >= c) return;
    const int tid = threadIdx.x;

    if (tid < BM) {
        const int i = m0 + tid;
        rows_s[tid] = perm[e * CAP + (i < c ? i : c - 1)];
    }
    __syncthreads();

    const int lane = tid & 63;
    const int w = tid >> 6;                    // wave 0..7
    const int srow = tid >> 3;                 // staging row 0..63
    const int us = ((tid & 7) ^ (srow & 7)) * 8;   // pre-swizzled source unit

    const unsigned short* bp = w1t + ((size_t)e * F_DIM + nb * BN) * H_DIM;
    const unsigned short* pA[4];
    const unsigned short* pB[4];
    int dA[4], dB[4];
#pragma unroll
    for (int i = 0; i < 4; ++i) {
        const int r = (i >> 1) * 128 + (i & 1) * 64 + srow;
        pA[i] = xb + (size_t)rows_s[r] * H_DIM + us;
        pB[i] = bp + (size_t)r * H_DIM + us;
        dA[i] = (r - srow + w * 8) * 64 + lane * 8;          // wave-uniform + lane*16B
        dB[i] = 16384 + dA[i];
    }

    f32x4 acc[8][4];
#pragma unroll
    for (int m = 0; m < 8; ++m)
#pragma unroll
        for (int n = 0; n < 4; ++n) acc[m][n] = (f32x4){0.f, 0.f, 0.f, 0.f};

    const int wm = w >> 2;                     // token half (0..1)
    const int wn = w & 3;                      // f quarter (0..3)
    const int fr = lane & 15;
    const int fg = lane >> 4;
    short8v b[2][4], a[2][2];

    KLOOP_PIPE(H_DIM / BK);                    // 16 K-tiles

    // epilogue: thread holds 4 consecutive f at fixed token -> packed 8B stores
    const size_t hrow0 = (size_t)offs[e] + m0;
#pragma unroll
    for (int n = 0; n < 4; ++n) {
        const int f = nb * BN + wn * 64 + n * 16 + fg * 4;
        const float4 bv = *(const float4*)(b1 + e * F_DIM + f);
        const float bb[4] = {bv.x, bv.y, bv.z, bv.w};
#pragma unroll
        for (int m = 0; m < 8; ++m) {
            const int tl = wm * 128 + m * 16 + fr;
            ushort4 o;
#pragma unroll
            for (int r = 0; r < 4; ++r) {
                const float xv = acc[m][n][r] + bb[r];
                const float g = 0.5f * xv * (1.f + erff(xv * 0.70710678118f));
                ((unsigned short*)&o)[r] = f2bf(g);
            }
            *(ushort4*)(hbuf + (hrow0 + tl) * F_DIM + f) = o;
        }
    }
}

// ================= GEMM2: ybuf[row] = h @ W2[e] + b2[e] (fp32, no atomics) =================
__global__ __launch_bounds__(512, 2) void gemm2_k(
    const unsigned short* __restrict__ hbuf, // [rows][F] bf16
    const unsigned short* __restrict__ w2t,  // [E][H][F] bf16 (pre-transposed)
    const float* __restrict__ b2,            // [E][H]
    float* __restrict__ ybuf,                // [rows][H] fp32
    const int* __restrict__ cnt, const int* __restrict__ offs)
{
    __shared__ __align__(16) unsigned short smem[65536];

    constexpr int NY = H_DIM / BN;             // 4
    constexpr int nwg = MBLK * NY * NE;        // 512
    const int bid = blockIdx.x;
    const int wg = (bid & 7) * (nwg >> 3) + (bid >> 3);
    const int e  = wg / (MBLK * NY);
    const int rem = wg % (MBLK * NY);
    const int nb = rem / MBLK;
    const int mb = rem % MBLK;

    const int c = cnt[e];
    const int m0 = mb * BM;
    if (m0 >= c) return;
    const int tid = threadIdx.x;

    const int lane = tid & 63;
    const int w = tid >> 6;
    const int srow = tid >> 3;
    const int us = ((tid & 7) ^ (srow & 7)) * 8;

    const size_t arow0 = (size_t)offs[e] + m0;
    const unsigned short* bp = w2t + ((size_t)e * H_DIM + nb * BN) * F_DIM;
    const unsigned short* pA[4];
    const unsigned short* pB[4];
    int dA[4], dB[4];
#pragma unroll
    for (int i = 0; i < 4; ++i) {
        const int r = (i >> 1) * 128 + (i & 1) * 64 + srow;
        pA[i] = hbuf + (arow0 + r) * F_DIM + us;
        pB[i] = bp + (size_t)r * F_DIM + us;
        dA[i] = (r - srow + w * 8) * 64 + lane * 8;
        dB[i] = 16384 + dA[i];
    }

    f32x4 acc[8][4];
#pragma unroll
    for (int m = 0; m < 8; ++m)
#pragma unroll
        for (int n = 0; n < 4; ++n) acc[m][n] = (f32x4){0.f, 0.f, 0.f, 0.f};

    const int wm = w >> 2;
    const int wn = w & 3;
    const int fr = lane & 15;
    const int fg = lane >> 4;
    short8v b[2][4], a[2][2];

    KLOOP_PIPE(F_DIM / BK);                    // 64 K-tiles

    // epilogue: packed float4 stores (bias folded, weights applied in combine_k)
#pragma unroll
    for (int n = 0; n < 4; ++n) {
        const int h = nb * BN + wn * 64 + n * 16 + fg * 4;
        const float4 bv = *(const float4*)(b2 + e * H_DIM + h);
#pragma unroll
        for (int m = 0; m < 8; ++m) {
            const int tl = wm * 128 + m * 16 + fr;
            float4 o;
            o.x = acc[m][n][0] + bv.x;
            o.y = acc[m][n][1] + bv.y;
            o.z = acc[m][n][2] + bv.z;
            o.w = acc[m][n][3] + bv.w;
            *(float4*)(ybuf + (arow0 + tl) * H_DIM + h) = o;
        }
    }
}

// ---------------- combine: out[t] = w0*y[slot0] + w1*y[slot1] ----------------
__global__ __launch_bounds__(256) void combine_k(
    const float* __restrict__ ybuf, const int* __restrict__ inv,
    const float* __restrict__ tw, const int* __restrict__ offs,
    float* __restrict__ out)
{
    const int t = blockIdx.x;
    const int j = threadIdx.x;          // 256 threads x float4 = 1024 = H
    const int i0 = inv[2 * t], i1 = inv[2 * t + 1];
    const float w0 = tw[2 * t], w1 = tw[2 * t + 1];
    const size_t r0 = (size_t)offs[i0 >> 13] + (i0 & 8191);
    const size_t r1 = (size_t)offs[i1 >> 13] + (i1 & 8191);
    const float4 a = *(const float4*)(ybuf + r0 * H_DIM + j * 4);
    const float4 b = *(const float4*)(ybuf + r1 * H_DIM + j * 4);
    float4 o;
    o.x = w0 * a.x + w1 * b.x;
    o.y = w0 * a.y + w1 * b.y;
    o.z = w0 * a.z + w1 * b.z;
    o.w = w0 * a.w + w1 * b.w;
    *(float4*)(out + (size_t)t * H_DIM + j * 4) = o;
}

extern "C" void kernel_launch(void* const* d_in, const int* in_sizes, int n_in,
                              void* d_out, int out_size, void* d_ws, size_t ws_size,
                              hipStream_t stream)
{
    const float* x  = (const float*)d_in[0];
    const float* Wr = (const float*)d_in[1];
    const float* br = (const float*)d_in[2];
    const float* W1 = (const float*)d_in[3];
    const float* b1 = (const float*)d_in[4];
    const float* W2 = (const float*)d_in[5];
    const float* b2 = (const float*)d_in[6];
    float* out = (float*)d_out;

    char* ws = (char*)d_ws;
    size_t off = 0;
    auto alloc = [&](size_t bytes) {
        char* p = ws + off;
        off += (bytes + 255) & ~(size_t)255;
        return p;
    };
    // Order matters: ybuf aliases [w1t, xb] (dead after gemm1 completes).
    unsigned short* w2t  = (unsigned short*)alloc((size_t)NE * H_DIM * F_DIM * 2);  // 67 MB
    unsigned short* w1t  = (unsigned short*)alloc((size_t)NE * F_DIM * H_DIM * 2);  // 67 MB
    unsigned short* xb   = (unsigned short*)alloc((size_t)T_TOK * H_DIM * 2);       // 17 MB
    unsigned short* hbuf = (unsigned short*)alloc((size_t)(T_TOK * 2 + NE * BM) * F_DIM * 2); // 151 MB
    int*   cnt  = (int*)alloc(NE * 4);
    int*   offs = (int*)alloc((NE + 1) * 4);
    int*   perm = (int*)alloc((size_t)NE * CAP * 4);
    int*   inv  = (int*)alloc((size_t)T_TOK * 2 * 4);
    float* tw   = (float*)alloc((size_t)T_TOK * 2 * 4);
    float* ybuf = (float*)w1t;   // [rows][H] fp32, 75.5 MB < w1t+xb (84 MB)
    (void)ws_size; (void)in_sizes; (void)n_in; (void)out_size;

    hipMemsetAsync(cnt, 0, NE * 4, stream);
    router_k<<<T_TOK / 4, 256, 0, stream>>>(x, Wr, br, cnt, perm, inv, tw, xb);
    prefix_k<<<1, 64, 0, stream>>>(cnt, offs);
    tcvt_k<<<dim3(F_DIM / 64, H_DIM / 64, NE), 256, 0, stream>>>(W1, w1t, H_DIM, F_DIM);
    tcvt_k<<<dim3(H_DIM / 64, F_DIM / 64, NE), 256, 0, stream>>>(W2, w2t, F_DIM, H_DIM);
    gemm1_k<<<MBLK * (F_DIM / BN) * NE, 512, 0, stream>>>(xb, w1t, b1, hbuf, perm, cnt, offs);
    gemm2_k<<<MBLK * (H_DIM / BN) * NE, 512, 0, stream>>>(hbuf, w2t, b2, ybuf, cnt, offs);
    combine_k<<<T_TOK, 256, 0, stream>>>(ybuf, inv, tw, offs, out);
}

// Round 8
// 696.251 us; speedup vs baseline: 1.3554x; 1.3554x over previous
//
#include <hip/hip_runtime.h>
#include <cstdint>
#include <cmath>

#define T_TOK 8192
#define H_DIM 1024
#define F_DIM 4096
#define NE 8
#define CAP 8192        // perm capacity per expert
#define BK 64
#define BM 128          // token rows per block
#define BN 256          // output cols per block
#define MBLK 32         // max M-blocks (128-row) per expert (4096-token cap)

typedef __attribute__((ext_vector_type(8))) short short8v;
typedef __attribute__((ext_vector_type(4))) float f32x4;

static __device__ __forceinline__ unsigned short f2bf(float f) {
    union { float f; unsigned int u; } v; v.f = f;
    unsigned int r = v.u + 0x7FFFu + ((v.u >> 16) & 1u);  // RNE
    return (unsigned short)(r >> 16);
}

// Branch-free gelu: Abramowitz-Stegun 7.1.26 erf, |err| <= 1.5e-7 (vs erff's
// libm path: ~2x fewer VALU ops, no divergence). gelu(x)=0.5x(1+erf(x/sqrt2)).
static __device__ __forceinline__ float fast_gelu(float x) {
    const float s  = x * 0.70710678118f;
    const float as = fabsf(s);
    const float t  = __builtin_amdgcn_rcpf(fmaf(0.3275911f, as, 1.f));
    float p = fmaf(1.061405429f, t, -1.453152027f);
    p = fmaf(p, t, 1.421413741f);
    p = fmaf(p, t, -0.284496736f);
    p = fmaf(p, t, 0.254829592f);
    p = p * t;
    const float E = __expf(-as * as);
    const float erf_abs = fmaf(-p, E, 1.f);
    const float erf_s = copysignf(erf_abs, s);
    return 0.5f * x * (1.f + erf_s);
}

// async global->LDS, 16B per lane; LDS dest is wave-uniform base + lane*16,
// global src is per-lane (supports gather + pre-swizzled source).
static __device__ __forceinline__ void gl_lds16(const void* g, void* l) {
    __builtin_amdgcn_global_load_lds(
        (const __attribute__((address_space(1))) unsigned int*)g,
        (__attribute__((address_space(3))) unsigned int*)l, 16, 0, 0);
}

// ============ merged prologue: router + W1 transpose + W2 transpose ============
// All three are independent; one launch runs them concurrently at aggregate BW
// instead of stream-serial (~105us -> ~70us).
#define G_ROUT (T_TOK / 4)                  // 2048
#define G_TCVT ((F_DIM / 64) * (H_DIM / 64) * NE)   // 8192 per weight tensor

__global__ __launch_bounds__(256) void prep_k(
    const float* __restrict__ x, const float* __restrict__ Wr,
    const float* __restrict__ br,
    const float* __restrict__ W1, const float* __restrict__ W2,
    int* __restrict__ cnt, int* __restrict__ perm,
    int* __restrict__ inv, float* __restrict__ tw,
    unsigned short* __restrict__ xb,
    unsigned short* __restrict__ w1t, unsigned short* __restrict__ w2t)
{
    __shared__ float tile[64][65];
    const int bid = blockIdx.x;

    if (bid < G_ROUT) {
        // ---- router: logits, top-2, weights, compaction, inverse map, x->bf16 ----
        const int wave = threadIdx.x >> 6;
        const int lane = threadIdx.x & 63;
        const int t = bid * 4 + wave;
        const float* xr = x + (size_t)t * H_DIM;
        float acc[NE];
#pragma unroll
        for (int e = 0; e < NE; ++e) acc[e] = 0.f;
#pragma unroll
        for (int c0 = 0; c0 < H_DIM; c0 += 256) {
            const float4 v = *(const float4*)(xr + c0 + lane * 4);
            ushort4 ob;
            ob.x = f2bf(v.x); ob.y = f2bf(v.y); ob.z = f2bf(v.z); ob.w = f2bf(v.w);
            *(ushort4*)(xb + (size_t)t * H_DIM + c0 + lane * 4) = ob;
            const int hbase = c0 + lane * 4;
            float vv[4] = {v.x, v.y, v.z, v.w};
#pragma unroll
            for (int i = 0; i < 4; ++i) {
                const float4 w0 = *(const float4*)(Wr + (size_t)(hbase + i) * NE);
                const float4 w1 = *(const float4*)(Wr + (size_t)(hbase + i) * NE + 4);
                acc[0] += vv[i] * w0.x; acc[1] += vv[i] * w0.y;
                acc[2] += vv[i] * w0.z; acc[3] += vv[i] * w0.w;
                acc[4] += vv[i] * w1.x; acc[5] += vv[i] * w1.y;
                acc[6] += vv[i] * w1.z; acc[7] += vv[i] * w1.w;
            }
        }
#pragma unroll
        for (int off = 32; off > 0; off >>= 1) {
#pragma unroll
            for (int e = 0; e < NE; ++e) acc[e] += __shfl_xor(acc[e], off, 64);
        }
        if (lane == 0) {
#pragma unroll
            for (int e = 0; e < NE; ++e) acc[e] += br[e];
            int i0 = 0; float l0 = acc[0];
#pragma unroll
            for (int e = 1; e < NE; ++e) if (acc[e] > l0) { l0 = acc[e]; i0 = e; }
            int i1 = -1; float l1 = -3.4e38f;
#pragma unroll
            for (int e = 0; e < NE; ++e) if (e != i0 && acc[e] > l1) { l1 = acc[e]; i1 = e; }
            // top-2 renormalized softmax weights from logits (exact)
            const float w0 = 1.f / (1.f + expf(l1 - l0));
            const int p0 = atomicAdd(&cnt[i0], 1);
            perm[i0 * CAP + p0] = t;
            const int p1 = atomicAdd(&cnt[i1], 1);
            perm[i1 * CAP + p1] = t;
            inv[2 * t + 0] = (i0 << 13) | p0;  tw[2 * t + 0] = w0;
            inv[2 * t + 1] = (i1 << 13) | p1;  tw[2 * t + 1] = 1.f - w0;
        }
        return;
    }

    // ---- transpose + fp32->bf16: in[E][R][C] -> out[E][C][R] (64x64 tiles) ----
    const float* in;
    unsigned short* out;
    int R, C, e, bx, by;
    if (bid < G_ROUT + G_TCVT) {
        const int j = bid - G_ROUT;
        in = W1; out = w1t; R = H_DIM; C = F_DIM;       // per e: (F/64)*(H/64)=1024
        e = j >> 10; const int rem = j & 1023;
        by = rem >> 6; bx = rem & 63;                   // by: H/64=16, bx: F/64=64
    } else {
        const int j = bid - G_ROUT - G_TCVT;
        in = W2; out = w2t; R = F_DIM; C = H_DIM;       // per e: (H/64)*(F/64)=1024
        e = j >> 10; const int rem = j & 1023;
        by = rem >> 4; bx = rem & 15;                   // by: F/64=64, bx: H/64=16
    }
    const int r0 = by * 64, c0 = bx * 64;
    const float* ip = in + (size_t)e * R * C;
    unsigned short* op = out + (size_t)e * R * C;
    const int jj = threadIdx.x;
    const int lr = jj >> 4, lc = (jj & 15) * 4;
#pragma unroll
    for (int p = 0; p < 4; ++p) {
        const float4 v = *(const float4*)(ip + (size_t)(r0 + lr + p * 16) * C + c0 + lc);
        tile[lr + p * 16][lc + 0] = v.x;
        tile[lr + p * 16][lc + 1] = v.y;
        tile[lr + p * 16][lc + 2] = v.z;
        tile[lr + p * 16][lc + 3] = v.w;
    }
    __syncthreads();
#pragma unroll
    for (int p = 0; p < 4; ++p) {
        const int orow = lr + p * 16;
        ushort4 o;
        o.x = f2bf(tile[lc + 0][orow]);
        o.y = f2bf(tile[lc + 1][orow]);
        o.z = f2bf(tile[lc + 2][orow]);
        o.w = f2bf(tile[lc + 3][orow]);
        *(ushort4*)(op + (size_t)(c0 + orow) * R + r0 + lc) = o;
    }
}

// ---------------- 128-aligned exclusive prefix of counts ----------------
__global__ void prefix_k(const int* __restrict__ cnt, int* __restrict__ offs)
{
    if (threadIdx.x == 0 && blockIdx.x == 0) {
        int o = 0;
        for (int e = 0; e < NE; ++e) { offs[e] = o; o += ((cnt[e] + 127) >> 7) << 7; }
        offs[NE] = o;
    }
}

// ================= GEMM1: h = gelu(gather(x) @ W1[e] + b1[e]) =================
// 128x256 tile, 4 waves (2M x 2N), wave-tile 64x128. Single-buffer BK=64
// (48KB LDS, 2 blocks/CU), global_load_lds staging, XOR-swizzled source+read,
// swapped-operand MFMA -> packed 8B stores along f. (r6 core, proven best.)
__global__ __launch_bounds__(256, 2) void gemm1_k(
    const unsigned short* __restrict__ xb,   // [T][H] bf16
    const unsigned short* __restrict__ w1t,  // [E][F][H] bf16 (pre-transposed)
    const float* __restrict__ b1,            // [E][F]
    unsigned short* __restrict__ hbuf,       // [rows][F] bf16
    const int* __restrict__ perm, const int* __restrict__ cnt, const int* __restrict__ offs)
{
    __shared__ __align__(16) unsigned short smem[(BM + BN) * BK];  // A 16KB | B 32KB
    __shared__ int rows_s[BM];

    constexpr int NY = F_DIM / BN;             // 16
    constexpr int nwg = MBLK * NY * NE;        // 4096
    const int bid = blockIdx.x;
    const int wg = (bid & 7) * (nwg >> 3) + (bid >> 3);   // XCD-aware bijective swizzle
    const int e  = wg / (MBLK * NY);
    const int rem = wg % (MBLK * NY);
    const int nb = rem / MBLK;
    const int mb = rem % MBLK;                 // fastest: same-XCD neighbors share B panel

    const int c = cnt[e];
    const int m0 = mb * BM;
    if (m0 >= c) return;
    const int tid = threadIdx.x;

    if (tid < BM) {
        const int i = m0 + tid;
        rows_s[tid] = perm[e * CAP + (i < c ? i : c - 1)];
    }
    __syncthreads();

    const int lane = tid & 63;
    const int w = tid >> 6;            // wave 0..3
    const int srow = tid >> 3;         // staging row-in-issue 0..31
    const int u = tid & 7;             // 16B unit within 128B row
    const int us = (u ^ (srow & 7)) * 8;   // pre-swizzled source unit (shorts)

    const unsigned short* bp = w1t + ((size_t)e * F_DIM + nb * BN) * H_DIM;
    const unsigned short* srcA[4];
    const unsigned short* srcB[8];
    int dstA[4], dstB[8];
#pragma unroll
    for (int j = 0; j < 4; ++j) {
        srcA[j] = xb + (size_t)rows_s[j * 32 + srow] * H_DIM + us;
        dstA[j] = (j * 32 + w * 8) * BK + lane * 8;          // wave-uniform LDS base
    }
#pragma unroll
    for (int j = 0; j < 8; ++j) {
        srcB[j] = bp + (size_t)(j * 32 + srow) * H_DIM + us;
        dstB[j] = BM * BK + (j * 32 + w * 8) * BK + lane * 8;
    }

    f32x4 acc[4][8];
#pragma unroll
    for (int m = 0; m < 4; ++m)
#pragma unroll
        for (int n = 0; n < 8; ++n) acc[m][n] = (f32x4){0.f, 0.f, 0.f, 0.f};

    const int wm = w >> 1;             // token half (0..1)
    const int wn = w & 1;              // f half (0..1)
    const int fr = lane & 15;
    const int fg = lane >> 4;
    const int fx = fr & 7;

    for (int k0 = 0; k0 < H_DIM; k0 += BK) {
#pragma unroll
        for (int j = 0; j < 4; ++j) gl_lds16(srcA[j] + k0, smem + dstA[j]);
#pragma unroll
        for (int j = 0; j < 8; ++j) gl_lds16(srcB[j] + k0, smem + dstB[j]);
        __syncthreads();   // drains vmcnt + barrier
        const unsigned short* A = smem;
        const unsigned short* B = smem + BM * BK;
#pragma unroll
        for (int kk = 0; kk < 2; ++kk) {
            const int q = kk * 4 + fg;
            const int ua = (q ^ fx) * 8;
            short8v a[4], b[8];
#pragma unroll
            for (int m = 0; m < 4; ++m)
                a[m] = *(const short8v*)(A + (wm * 64 + m * 16 + fr) * BK + ua);
#pragma unroll
            for (int n = 0; n < 8; ++n)
                b[n] = *(const short8v*)(B + (wn * 128 + n * 16 + fr) * BK + ua);
#pragma unroll
            for (int m = 0; m < 4; ++m)
#pragma unroll
                for (int n = 0; n < 8; ++n)   // swapped: C[f][token]
                    acc[m][n] = __builtin_amdgcn_mfma_f32_16x16x32_bf16(b[n], a[m], acc[m][n], 0, 0, 0);
        }
        __syncthreads();
    }

    // epilogue: thread holds 4 consecutive f at fixed token -> packed 8B stores
    const size_t hrow0 = (size_t)offs[e] + m0;
#pragma unroll
    for (int n = 0; n < 8; ++n) {
        const int f = nb * BN + wn * 128 + n * 16 + fg * 4;
        const float4 bv = *(const float4*)(b1 + e * F_DIM + f);
        const float bb[4] = {bv.x, bv.y, bv.z, bv.w};
#pragma unroll
        for (int m = 0; m < 4; ++m) {
            const int tl = wm * 64 + m * 16 + fr;
            ushort4 o;
#pragma unroll
            for (int r = 0; r < 4; ++r) {
                const float g = fast_gelu(acc[m][n][r] + bb[r]);
                ((unsigned short*)&o)[r] = f2bf(g);
            }
            *(ushort4*)(hbuf + (hrow0 + tl) * F_DIM + f) = o;
        }
    }
}

// ================= GEMM2: ybuf[row] = h @ W2[e] + b2[e] (fp32, no atomics) =================
__global__ __launch_bounds__(256, 2) void gemm2_k(
    const unsigned short* __restrict__ hbuf, // [rows][F] bf16
    const unsigned short* __restrict__ w2t,  // [E][H][F] bf16 (pre-transposed)
    const float* __restrict__ b2,            // [E][H]
    float* __restrict__ ybuf,                // [rows][H] fp32
    const int* __restrict__ cnt, const int* __restrict__ offs)
{
    __shared__ __align__(16) unsigned short smem[(BM + BN) * BK];

    constexpr int NY = H_DIM / BN;             // 4
    constexpr int nwg = MBLK * NY * NE;        // 1024
    const int bid = blockIdx.x;
    const int wg = (bid & 7) * (nwg >> 3) + (bid >> 3);
    const int e  = wg / (MBLK * NY);
    const int rem = wg % (MBLK * NY);
    const int nb = rem / MBLK;
    const int mb = rem % MBLK;

    const int c = cnt[e];
    const int m0 = mb * BM;
    if (m0 >= c) return;
    const int tid = threadIdx.x;

    const int lane = tid & 63;
    const int w = tid >> 6;
    const int srow = tid >> 3;
    const int u = tid & 7;
    const int us = (u ^ (srow & 7)) * 8;

    const size_t arow0 = (size_t)offs[e] + m0;
    const unsigned short* bp = w2t + ((size_t)e * H_DIM + nb * BN) * F_DIM;
    const unsigned short* srcA[4];
    const unsigned short* srcB[8];
    int dstA[4], dstB[8];
#pragma unroll
    for (int j = 0; j < 4; ++j) {
        srcA[j] = hbuf + (arow0 + j * 32 + srow) * F_DIM + us;
        dstA[j] = (j * 32 + w * 8) * BK + lane * 8;
    }
#pragma unroll
    for (int j = 0; j < 8; ++j) {
        srcB[j] = bp + (size_t)(j * 32 + srow) * F_DIM + us;
        dstB[j] = BM * BK + (j * 32 + w * 8) * BK + lane * 8;
    }

    f32x4 acc[4][8];
#pragma unroll
    for (int m = 0; m < 4; ++m)
#pragma unroll
        for (int n = 0; n < 8; ++n) acc[m][n] = (f32x4){0.f, 0.f, 0.f, 0.f};

    const int wm = w >> 1;
    const int wn = w & 1;
    const int fr = lane & 15;
    const int fg = lane >> 4;
    const int fx = fr & 7;

    for (int k0 = 0; k0 < F_DIM; k0 += BK) {
#pragma unroll
        for (int j = 0; j < 4; ++j) gl_lds16(srcA[j] + k0, smem + dstA[j]);
#pragma unroll
        for (int j = 0; j < 8; ++j) gl_lds16(srcB[j] + k0, smem + dstB[j]);
        __syncthreads();
        const unsigned short* A = smem;
        const unsigned short* B = smem + BM * BK;
#pragma unroll
        for (int kk = 0; kk < 2; ++kk) {
            const int q = kk * 4 + fg;
            const int ua = (q ^ fx) * 8;
            short8v a[4], b[8];
#pragma unroll
            for (int m = 0; m < 4; ++m)
                a[m] = *(const short8v*)(A + (wm * 64 + m * 16 + fr) * BK + ua);
#pragma unroll
            for (int n = 0; n < 8; ++n)
                b[n] = *(const short8v*)(B + (wn * 128 + n * 16 + fr) * BK + ua);
#pragma unroll
            for (int m = 0; m < 4; ++m)
#pragma unroll
                for (int n = 0; n < 8; ++n)
                    acc[m][n] = __builtin_amdgcn_mfma_f32_16x16x32_bf16(b[n], a[m], acc[m][n], 0, 0, 0);
        }
        __syncthreads();
    }

    // epilogue: packed float4 stores (bias folded, weights applied in combine_k)
#pragma unroll
    for (int n = 0; n < 8; ++n) {
        const int h = nb * BN + wn * 128 + n * 16 + fg * 4;
        const float4 bv = *(const float4*)(b2 + e * H_DIM + h);
#pragma unroll
        for (int m = 0; m < 4; ++m) {
            const int tl = wm * 64 + m * 16 + fr;
            float4 o;
            o.x = acc[m][n][0] + bv.x;
            o.y = acc[m][n][1] + bv.y;
            o.z = acc[m][n][2] + bv.z;
            o.w = acc[m][n][3] + bv.w;
            *(float4*)(ybuf + (arow0 + tl) * H_DIM + h) = o;
        }
    }
}

// ---------------- combine: out[t] = w0*y[slot0] + w1*y[slot1] ----------------
__global__ __launch_bounds__(256) void combine_k(
    const float* __restrict__ ybuf, const int* __restrict__ inv,
    const float* __restrict__ tw, const int* __restrict__ offs,
    float* __restrict__ out)
{
    const int t = blockIdx.x;
    const int j = threadIdx.x;          // 256 threads x float4 = 1024 = H
    const int i0 = inv[2 * t], i1 = inv[2 * t + 1];
    const float w0 = tw[2 * t], w1 = tw[2 * t + 1];
    const size_t r0 = (size_t)offs[i0 >> 13] + (i0 & 8191);
    const size_t r1 = (size_t)offs[i1 >> 13] + (i1 & 8191);
    const float4 a = *(const float4*)(ybuf + r0 * H_DIM + j * 4);
    const float4 b = *(const float4*)(ybuf + r1 * H_DIM + j * 4);
    float4 o;
    o.x = w0 * a.x + w1 * b.x;
    o.y = w0 * a.y + w1 * b.y;
    o.z = w0 * a.z + w1 * b.z;
    o.w = w0 * a.w + w1 * b.w;
    *(float4*)(out + (size_t)t * H_DIM + j * 4) = o;
}

extern "C" void kernel_launch(void* const* d_in, const int* in_sizes, int n_in,
                              void* d_out, int out_size, void* d_ws, size_t ws_size,
                              hipStream_t stream)
{
    const float* x  = (const float*)d_in[0];
    const float* Wr = (const float*)d_in[1];
    const float* br = (const float*)d_in[2];
    const float* W1 = (const float*)d_in[3];
    const float* b1 = (const float*)d_in[4];
    const float* W2 = (const float*)d_in[5];
    const float* b2 = (const float*)d_in[6];
    float* out = (float*)d_out;

    char* ws = (char*)d_ws;
    size_t off = 0;
    auto alloc = [&](size_t bytes) {
        char* p = ws + off;
        off += (bytes + 255) & ~(size_t)255;
        return p;
    };
    // Order matters: ybuf aliases [w1t, xb] (dead after gemm1 completes).
    unsigned short* w2t  = (unsigned short*)alloc((size_t)NE * H_DIM * F_DIM * 2);  // 67 MB
    unsigned short* w1t  = (unsigned short*)alloc((size_t)NE * F_DIM * H_DIM * 2);  // 67 MB
    unsigned short* xb   = (unsigned short*)alloc((size_t)T_TOK * H_DIM * 2);       // 17 MB
    unsigned short* hbuf = (unsigned short*)alloc((size_t)(T_TOK * 2 + NE * BM) * F_DIM * 2); // 143 MB
    int*   cnt  = (int*)alloc(NE * 4);
    int*   offs = (int*)alloc((NE + 1) * 4);
    int*   perm = (int*)alloc((size_t)NE * CAP * 4);
    int*   inv  = (int*)alloc((size_t)T_TOK * 2 * 4);
    float* tw   = (float*)alloc((size_t)T_TOK * 2 * 4);
    float* ybuf = (float*)w1t;   // [rows][H] fp32, 71 MB < w1t+xb (84 MB)
    (void)ws_size; (void)in_sizes; (void)n_in; (void)out_size;

    hipMemsetAsync(cnt, 0, NE * 4, stream);
    prep_k<<<G_ROUT + 2 * G_TCVT, 256, 0, stream>>>(x, Wr, br, W1, W2,
                                                    cnt, perm, inv, tw, xb, w1t, w2t);
    prefix_k<<<1, 64, 0, stream>>>(cnt, offs);
    gemm1_k<<<MBLK * (F_DIM / BN) * NE, 256, 0, stream>>>(xb, w1t, b1, hbuf, perm, cnt, offs);
    gemm2_k<<<MBLK * (H_DIM / BN) * NE, 256, 0, stream>>>(hbuf, w2t, b2, ybuf, cnt, offs);
    combine_k<<<T_TOK, 256, 0, stream>>>(ybuf, inv, tw, offs, out);
}

// Round 9
// 685.162 us; speedup vs baseline: 1.3773x; 1.0162x over previous
//
#include <hip/hip_runtime.h>
#include <cstdint>
#include <cmath>

#define T_TOK 8192
#define H_DIM 1024
#define F_DIM 4096
#define NE 8
#define CAP 8192        // perm capacity per expert
#define BK 64
#define BM 128          // token rows per block
#define BN 256          // output cols per block
#define MBLK 32         // max M-blocks (128-row) per expert (4096-token cap)

typedef __attribute__((ext_vector_type(8))) short short8v;
typedef __attribute__((ext_vector_type(4))) float f32x4;

static __device__ __forceinline__ unsigned short f2bf(float f) {
    union { float f; unsigned int u; } v; v.f = f;
    unsigned int r = v.u + 0x7FFFu + ((v.u >> 16) & 1u);  // RNE
    return (unsigned short)(r >> 16);
}

static __device__ __forceinline__ float bf2f(unsigned short u) {
    union { unsigned int i; float f; } v; v.i = ((unsigned)u) << 16; return v.f;
}

// Branch-free gelu: Abramowitz-Stegun 7.1.26 erf, |err| <= 1.5e-7.
static __device__ __forceinline__ float fast_gelu(float x) {
    const float s  = x * 0.70710678118f;
    const float as = fabsf(s);
    const float t  = __builtin_amdgcn_rcpf(fmaf(0.3275911f, as, 1.f));
    float p = fmaf(1.061405429f, t, -1.453152027f);
    p = fmaf(p, t, 1.421413741f);
    p = fmaf(p, t, -0.284496736f);
    p = fmaf(p, t, 0.254829592f);
    p = p * t;
    const float E = __expf(-as * as);
    const float erf_abs = fmaf(-p, E, 1.f);
    const float erf_s = copysignf(erf_abs, s);
    return 0.5f * x * (1.f + erf_s);
}

// async global->LDS, 16B per lane; LDS dest is wave-uniform base + lane*16,
// global src is per-lane (supports gather + pre-swizzled source).
static __device__ __forceinline__ void gl_lds16(const void* g, void* l) {
    __builtin_amdgcn_global_load_lds(
        (const __attribute__((address_space(1))) unsigned int*)g,
        (__attribute__((address_space(3))) unsigned int*)l, 16, 0, 0);
}

// ============ merged prologue: router + W1 transpose + W2 transpose ============
#define G_ROUT (T_TOK / 4)   // 2048 router blocks (4 tokens each)
#define G_TC   4096          // per weight tensor: (C/64)*(R/128)*E transpose blocks
#define LDK    140           // LDS tile col-stride (shorts); gives floor-rate banks

__global__ __launch_bounds__(256) void prep_k(
    const float* __restrict__ x, const float* __restrict__ Wr,
    const float* __restrict__ br,
    const float* __restrict__ W1, const float* __restrict__ W2,
    int* __restrict__ cnt, int* __restrict__ perm,
    int* __restrict__ inv, float* __restrict__ tw,
    unsigned short* __restrict__ xb,
    unsigned short* __restrict__ w1t, unsigned short* __restrict__ w2t)
{
    __shared__ __align__(16) unsigned short tile_s[64 * LDK];  // [col][row] bf16
    const int bid = blockIdx.x;

    if (bid < G_ROUT) {
        // ---- router: logits, top-2, weights, compaction, inverse map, x->bf16 ----
        const int wave = threadIdx.x >> 6;
        const int lane = threadIdx.x & 63;
        const int t = bid * 4 + wave;
        const float* xr = x + (size_t)t * H_DIM;
        float acc[NE];
#pragma unroll
        for (int e = 0; e < NE; ++e) acc[e] = 0.f;
#pragma unroll
        for (int c0 = 0; c0 < H_DIM; c0 += 256) {
            const float4 v = *(const float4*)(xr + c0 + lane * 4);
            ushort4 ob;
            ob.x = f2bf(v.x); ob.y = f2bf(v.y); ob.z = f2bf(v.z); ob.w = f2bf(v.w);
            *(ushort4*)(xb + (size_t)t * H_DIM + c0 + lane * 4) = ob;
            const int hbase = c0 + lane * 4;
            float vv[4] = {v.x, v.y, v.z, v.w};
#pragma unroll
            for (int i = 0; i < 4; ++i) {
                const float4 w0 = *(const float4*)(Wr + (size_t)(hbase + i) * NE);
                const float4 w1 = *(const float4*)(Wr + (size_t)(hbase + i) * NE + 4);
                acc[0] += vv[i] * w0.x; acc[1] += vv[i] * w0.y;
                acc[2] += vv[i] * w0.z; acc[3] += vv[i] * w0.w;
                acc[4] += vv[i] * w1.x; acc[5] += vv[i] * w1.y;
                acc[6] += vv[i] * w1.z; acc[7] += vv[i] * w1.w;
            }
        }
#pragma unroll
        for (int off = 32; off > 0; off >>= 1) {
#pragma unroll
            for (int e = 0; e < NE; ++e) acc[e] += __shfl_xor(acc[e], off, 64);
        }
        if (lane == 0) {
#pragma unroll
            for (int e = 0; e < NE; ++e) acc[e] += br[e];
            int i0 = 0; float l0 = acc[0];
#pragma unroll
            for (int e = 1; e < NE; ++e) if (acc[e] > l0) { l0 = acc[e]; i0 = e; }
            int i1 = -1; float l1 = -3.4e38f;
#pragma unroll
            for (int e = 0; e < NE; ++e) if (e != i0 && acc[e] > l1) { l1 = acc[e]; i1 = e; }
            // top-2 renormalized softmax weights from logits (exact)
            const float w0 = 1.f / (1.f + expf(l1 - l0));
            const int p0 = atomicAdd(&cnt[i0], 1);
            perm[i0 * CAP + p0] = t;
            const int p1 = atomicAdd(&cnt[i1], 1);
            perm[i1 * CAP + p1] = t;
            inv[2 * t + 0] = (i0 << 13) | p0;  tw[2 * t + 0] = w0;
            inv[2 * t + 1] = (i1 << 13) | p1;  tw[2 * t + 1] = 1.f - w0;
        }
        return;
    }

    // ---- transpose + fp32->bf16: in[E][R][C] -> out[E][C][R], 128x64 tiles ----
    // Reads: 256B row segments. Writes: 256B (128-short) output row segments.
    // LDS [col][row] bf16, in-register 4x4 micro-transpose, ds_write_b64 /
    // ds_read_b64 at the bank floor (LDK=140 spreads bank pairs uniformly).
    const float* in;
    unsigned short* out;
    int R, C, e, bx, by;
    if (bid < G_ROUT + G_TC) {
        const int j = bid - G_ROUT;
        in = W1; out = w1t; R = H_DIM; C = F_DIM;   // per e: 64 cbl x 8 rbl = 512
        e = j >> 9; const int rem = j & 511;
        bx = rem & 63; by = rem >> 6;
    } else {
        const int j = bid - G_ROUT - G_TC;
        in = W2; out = w2t; R = F_DIM; C = H_DIM;   // per e: 16 cbl x 32 rbl = 512
        e = j >> 9; const int rem = j & 511;
        bx = rem & 15; by = rem >> 4;
    }
    const int r0 = by * 128, c0 = bx * 64;
    const int colg = threadIdx.x & 15;              // 16 col-groups of 4
    const int rowg = threadIdx.x >> 4;              // 16 row-groups of 4 (x2)
    const float* ip = in + (size_t)e * R * C + (size_t)r0 * C + c0;
#pragma unroll
    for (int p = 0; p < 2; ++p) {
        const int rr = (rowg + p * 16) * 4;
        const float4 v0 = *(const float4*)(ip + (size_t)(rr + 0) * C + colg * 4);
        const float4 v1 = *(const float4*)(ip + (size_t)(rr + 1) * C + colg * 4);
        const float4 v2 = *(const float4*)(ip + (size_t)(rr + 2) * C + colg * 4);
        const float4 v3 = *(const float4*)(ip + (size_t)(rr + 3) * C + colg * 4);
        const float rv[4][4] = {{v0.x, v0.y, v0.z, v0.w}, {v1.x, v1.y, v1.z, v1.w},
                                {v2.x, v2.y, v2.z, v2.w}, {v3.x, v3.y, v3.z, v3.w}};
#pragma unroll
        for (int ci = 0; ci < 4; ++ci) {
            ushort4 o;
            o.x = f2bf(rv[0][ci]); o.y = f2bf(rv[1][ci]);
            o.z = f2bf(rv[2][ci]); o.w = f2bf(rv[3][ci]);
            *(ushort4*)(tile_s + (colg * 4 + ci) * LDK + rr) = o;
        }
    }
    __syncthreads();
    unsigned short* op = out + (size_t)e * R * C + (size_t)c0 * R + r0;
#pragma unroll
    for (int p = 0; p < 4; ++p) {
        const int c = (threadIdx.x >> 4) + p * 16;  // out row (input col) 0..63
        const int s = (threadIdx.x & 15) * 8;       // 16 lanes x 16B = 256B/row
        const unsigned short* sp = tile_s + c * LDK + s;
        const uint2 w0 = *(const uint2*)(sp);
        const uint2 w1 = *(const uint2*)(sp + 4);
        uint4 o4; o4.x = w0.x; o4.y = w0.y; o4.z = w1.x; o4.w = w1.y;
        *(uint4*)(op + (size_t)c * R + s) = o4;
    }
}

// ---------------- 128-aligned exclusive prefix of counts ----------------
__global__ void prefix_k(const int* __restrict__ cnt, int* __restrict__ offs)
{
    if (threadIdx.x == 0 && blockIdx.x == 0) {
        int o = 0;
        for (int e = 0; e < NE; ++e) { offs[e] = o; o += ((cnt[e] + 127) >> 7) << 7; }
        offs[NE] = o;
    }
}

// ================= GEMM1: h = gelu(gather(x) @ W1[e] + b1[e]) =================
// 128x256 tile, 4 waves (2M x 2N), wave-tile 64x128. Single-buffer BK=64
// (48KB LDS, 2 blocks/CU), global_load_lds staging, XOR-swizzled source+read,
// swapped-operand MFMA -> packed 8B stores along f. (r6/r8 core, proven best.)
__global__ __launch_bounds__(256, 2) void gemm1_k(
    const unsigned short* __restrict__ xb,   // [T][H] bf16
    const unsigned short* __restrict__ w1t,  // [E][F][H] bf16 (pre-transposed)
    const float* __restrict__ b1,            // [E][F]
    unsigned short* __restrict__ hbuf,       // [rows][F] bf16
    const int* __restrict__ perm, const int* __restrict__ cnt, const int* __restrict__ offs)
{
    __shared__ __align__(16) unsigned short smem[(BM + BN) * BK];  // A 16KB | B 32KB
    __shared__ int rows_s[BM];

    constexpr int NY = F_DIM / BN;             // 16
    constexpr int nwg = MBLK * NY * NE;        // 4096
    const int bid = blockIdx.x;
    const int wg = (bid & 7) * (nwg >> 3) + (bid >> 3);   // XCD-aware bijective swizzle
    const int e  = wg / (MBLK * NY);
    const int rem = wg % (MBLK * NY);
    const int nb = rem / MBLK;
    const int mb = rem % MBLK;                 // fastest: same-XCD neighbors share B panel

    const int c = cnt[e];
    const int m0 = mb * BM;
    if (m0 >= c) return;
    const int tid = threadIdx.x;

    if (tid < BM) {
        const int i = m0 + tid;
        rows_s[tid] = perm[e * CAP + (i < c ? i : c - 1)];
    }
    __syncthreads();

    const int lane = tid & 63;
    const int w = tid >> 6;            // wave 0..3
    const int srow = tid >> 3;         // staging row-in-issue 0..31
    const int u = tid & 7;             // 16B unit within 128B row
    const int us = (u ^ (srow & 7)) * 8;   // pre-swizzled source unit (shorts)

    const unsigned short* bp = w1t + ((size_t)e * F_DIM + nb * BN) * H_DIM;
    const unsigned short* srcA[4];
    const unsigned short* srcB[8];
    int dstA[4], dstB[8];
#pragma unroll
    for (int j = 0; j < 4; ++j) {
        srcA[j] = xb + (size_t)rows_s[j * 32 + srow] * H_DIM + us;
        dstA[j] = (j * 32 + w * 8) * BK + lane * 8;          // wave-uniform LDS base
    }
#pragma unroll
    for (int j = 0; j < 8; ++j) {
        srcB[j] = bp + (size_t)(j * 32 + srow) * H_DIM + us;
        dstB[j] = BM * BK + (j * 32 + w * 8) * BK + lane * 8;
    }

    f32x4 acc[4][8];
#pragma unroll
    for (int m = 0; m < 4; ++m)
#pragma unroll
        for (int n = 0; n < 8; ++n) acc[m][n] = (f32x4){0.f, 0.f, 0.f, 0.f};

    const int wm = w >> 1;             // token half (0..1)
    const int wn = w & 1;              // f half (0..1)
    const int fr = lane & 15;
    const int fg = lane >> 4;
    const int fx = fr & 7;

    for (int k0 = 0; k0 < H_DIM; k0 += BK) {
#pragma unroll
        for (int j = 0; j < 4; ++j) gl_lds16(srcA[j] + k0, smem + dstA[j]);
#pragma unroll
        for (int j = 0; j < 8; ++j) gl_lds16(srcB[j] + k0, smem + dstB[j]);
        __syncthreads();   // drains vmcnt + barrier
        const unsigned short* A = smem;
        const unsigned short* B = smem + BM * BK;
#pragma unroll
        for (int kk = 0; kk < 2; ++kk) {
            const int q = kk * 4 + fg;
            const int ua = (q ^ fx) * 8;
            short8v a[4], b[8];
#pragma unroll
            for (int m = 0; m < 4; ++m)
                a[m] = *(const short8v*)(A + (wm * 64 + m * 16 + fr) * BK + ua);
#pragma unroll
            for (int n = 0; n < 8; ++n)
                b[n] = *(const short8v*)(B + (wn * 128 + n * 16 + fr) * BK + ua);
#pragma unroll
            for (int m = 0; m < 4; ++m)
#pragma unroll
                for (int n = 0; n < 8; ++n)   // swapped: C[f][token]
                    acc[m][n] = __builtin_amdgcn_mfma_f32_16x16x32_bf16(b[n], a[m], acc[m][n], 0, 0, 0);
        }
        __syncthreads();
    }

    // epilogue: thread holds 4 consecutive f at fixed token -> packed 8B stores
    const size_t hrow0 = (size_t)offs[e] + m0;
#pragma unroll
    for (int n = 0; n < 8; ++n) {
        const int f = nb * BN + wn * 128 + n * 16 + fg * 4;
        const float4 bv = *(const float4*)(b1 + e * F_DIM + f);
        const float bb[4] = {bv.x, bv.y, bv.z, bv.w};
#pragma unroll
        for (int m = 0; m < 4; ++m) {
            const int tl = wm * 64 + m * 16 + fr;
            ushort4 o;
#pragma unroll
            for (int r = 0; r < 4; ++r) {
                const float g = fast_gelu(acc[m][n][r] + bb[r]);
                ((unsigned short*)&o)[r] = f2bf(g);
            }
            *(ushort4*)(hbuf + (hrow0 + tl) * F_DIM + f) = o;
        }
    }
}

// ================= GEMM2: ybuf[row] = h @ W2[e] + b2[e] (bf16, no atomics) =================
__global__ __launch_bounds__(256, 2) void gemm2_k(
    const unsigned short* __restrict__ hbuf, // [rows][F] bf16
    const unsigned short* __restrict__ w2t,  // [E][H][F] bf16 (pre-transposed)
    const float* __restrict__ b2,            // [E][H]
    unsigned short* __restrict__ ybuf,       // [rows][H] bf16
    const int* __restrict__ cnt, const int* __restrict__ offs)
{
    __shared__ __align__(16) unsigned short smem[(BM + BN) * BK];

    constexpr int NY = H_DIM / BN;             // 4
    constexpr int nwg = MBLK * NY * NE;        // 1024
    const int bid = blockIdx.x;
    const int wg = (bid & 7) * (nwg >> 3) + (bid >> 3);
    const int e  = wg / (MBLK * NY);
    const int rem = wg % (MBLK * NY);
    const int nb = rem / MBLK;
    const int mb = rem % MBLK;

    const int c = cnt[e];
    const int m0 = mb * BM;
    if (m0 >= c) return;
    const int tid = threadIdx.x;

    const int lane = tid & 63;
    const int w = tid >> 6;
    const int srow = tid >> 3;
    const int u = tid & 7;
    const int us = (u ^ (srow & 7)) * 8;

    const size_t arow0 = (size_t)offs[e] + m0;
    const unsigned short* bp = w2t + ((size_t)e * H_DIM + nb * BN) * F_DIM;
    const unsigned short* srcA[4];
    const unsigned short* srcB[8];
    int dstA[4], dstB[8];
#pragma unroll
    for (int j = 0; j < 4; ++j) {
        srcA[j] = hbuf + (arow0 + j * 32 + srow) * F_DIM + us;
        dstA[j] = (j * 32 + w * 8) * BK + lane * 8;
    }
#pragma unroll
    for (int j = 0; j < 8; ++j) {
        srcB[j] = bp + (size_t)(j * 32 + srow) * F_DIM + us;
        dstB[j] = BM * BK + (j * 32 + w * 8) * BK + lane * 8;
    }

    f32x4 acc[4][8];
#pragma unroll
    for (int m = 0; m < 4; ++m)
#pragma unroll
        for (int n = 0; n < 8; ++n) acc[m][n] = (f32x4){0.f, 0.f, 0.f, 0.f};

    const int wm = w >> 1;
    const int wn = w & 1;
    const int fr = lane & 15;
    const int fg = lane >> 4;
    const int fx = fr & 7;

    for (int k0 = 0; k0 < F_DIM; k0 += BK) {
#pragma unroll
        for (int j = 0; j < 4; ++j) gl_lds16(srcA[j] + k0, smem + dstA[j]);
#pragma unroll
        for (int j = 0; j < 8; ++j) gl_lds16(srcB[j] + k0, smem + dstB[j]);
        __syncthreads();
        const unsigned short* A = smem;
        const unsigned short* B = smem + BM * BK;
#pragma unroll
        for (int kk = 0; kk < 2; ++kk) {
            const int q = kk * 4 + fg;
            const int ua = (q ^ fx) * 8;
            short8v a[4], b[8];
#pragma unroll
            for (int m = 0; m < 4; ++m)
                a[m] = *(const short8v*)(A + (wm * 64 + m * 16 + fr) * BK + ua);
#pragma unroll
            for (int n = 0; n < 8; ++n)
                b[n] = *(const short8v*)(B + (wn * 128 + n * 16 + fr) * BK + ua);
#pragma unroll
            for (int m = 0; m < 4; ++m)
#pragma unroll
                for (int n = 0; n < 8; ++n)
                    acc[m][n] = __builtin_amdgcn_mfma_f32_16x16x32_bf16(b[n], a[m], acc[m][n], 0, 0, 0);
        }
        __syncthreads();
    }

    // epilogue: packed bf16 ushort4 stores (bias folded; weights in combine_k)
#pragma unroll
    for (int n = 0; n < 8; ++n) {
        const int h = nb * BN + wn * 128 + n * 16 + fg * 4;
        const float4 bv = *(const float4*)(b2 + e * H_DIM + h);
#pragma unroll
        for (int m = 0; m < 4; ++m) {
            const int tl = wm * 64 + m * 16 + fr;
            ushort4 o;
            o.x = f2bf(acc[m][n][0] + bv.x);
            o.y = f2bf(acc[m][n][1] + bv.y);
            o.z = f2bf(acc[m][n][2] + bv.z);
            o.w = f2bf(acc[m][n][3] + bv.w);
            *(ushort4*)(ybuf + (arow0 + tl) * H_DIM + h) = o;
        }
    }
}

// ---------------- combine: out[t] = w0*y[slot0] + w1*y[slot1] ----------------
__global__ __launch_bounds__(256) void combine_k(
    const unsigned short* __restrict__ ybuf, const int* __restrict__ inv,
    const float* __restrict__ tw, const int* __restrict__ offs,
    float* __restrict__ out)
{
    const int t = blockIdx.x;
    const int j = threadIdx.x;          // 256 threads x 4 bf16 = 1024 = H
    const int i0 = inv[2 * t], i1 = inv[2 * t + 1];
    const float w0 = tw[2 * t], w1 = tw[2 * t + 1];
    const size_t r0 = (size_t)offs[i0 >> 13] + (i0 & 8191);
    const size_t r1 = (size_t)offs[i1 >> 13] + (i1 & 8191);
    const ushort4 a = *(const ushort4*)(ybuf + r0 * H_DIM + j * 4);
    const ushort4 b = *(const ushort4*)(ybuf + r1 * H_DIM + j * 4);
    float4 o;
    o.x = w0 * bf2f(a.x) + w1 * bf2f(b.x);
    o.y = w0 * bf2f(a.y) + w1 * bf2f(b.y);
    o.z = w0 * bf2f(a.z) + w1 * bf2f(b.z);
    o.w = w0 * bf2f(a.w) + w1 * bf2f(b.w);
    *(float4*)(out + (size_t)t * H_DIM + j * 4) = o;
}

extern "C" void kernel_launch(void* const* d_in, const int* in_sizes, int n_in,
                              void* d_out, int out_size, void* d_ws, size_t ws_size,
                              hipStream_t stream)
{
    const float* x  = (const float*)d_in[0];
    const float* Wr = (const float*)d_in[1];
    const float* br = (const float*)d_in[2];
    const float* W1 = (const float*)d_in[3];
    const float* b1 = (const float*)d_in[4];
    const float* W2 = (const float*)d_in[5];
    const float* b2 = (const float*)d_in[6];
    float* out = (float*)d_out;

    char* ws = (char*)d_ws;
    size_t off = 0;
    auto alloc = [&](size_t bytes) {
        char* p = ws + off;
        off += (bytes + 255) & ~(size_t)255;
        return p;
    };
    // Order matters: ybuf aliases w1t (dead after gemm1 completes).
    unsigned short* w2t  = (unsigned short*)alloc((size_t)NE * H_DIM * F_DIM * 2);  // 67 MB
    unsigned short* w1t  = (unsigned short*)alloc((size_t)NE * F_DIM * H_DIM * 2);  // 67 MB
    unsigned short* xb   = (unsigned short*)alloc((size_t)T_TOK * H_DIM * 2);       // 17 MB
    unsigned short* hbuf = (unsigned short*)alloc((size_t)(T_TOK * 2 + NE * BM) * F_DIM * 2); // 143 MB
    int*   cnt  = (int*)alloc(NE * 4);
    int*   offs = (int*)alloc((NE + 1) * 4);
    int*   perm = (int*)alloc((size_t)NE * CAP * 4);
    int*   inv  = (int*)alloc((size_t)T_TOK * 2 * 4);
    float* tw   = (float*)alloc((size_t)T_TOK * 2 * 4);
    unsigned short* ybuf = w1t;   // [rows][H] bf16, 34 MB < w1t (67 MB)
    (void)ws_size; (void)in_sizes; (void)n_in; (void)out_size;

    hipMemsetAsync(cnt, 0, NE * 4, stream);
    prep_k<<<G_ROUT + 2 * G_TC, 256, 0, stream>>>(x, Wr, br, W1, W2,
                                                  cnt, perm, inv, tw, xb, w1t, w2t);
    prefix_k<<<1, 64, 0, stream>>>(cnt, offs);
    gemm1_k<<<MBLK * (F_DIM / BN) * NE, 256, 0, stream>>>(xb, w1t, b1, hbuf, perm, cnt, offs);
    gemm2_k<<<MBLK * (H_DIM / BN) * NE, 256, 0, stream>>>(hbuf, w2t, b2, ybuf, cnt, offs);
    combine_k<<<T_TOK, 256, 0, stream>>>(ybuf, inv, tw, offs, out);
}